// Round 7
// baseline (330.546 us; speedup 1.0000x reference)
//
#include <hip/hip_runtime.h>
#include <cstdint>
#include <cstddef>

typedef unsigned short ushort_t;
typedef __bf16 bf16x8 __attribute__((ext_vector_type(8)));
typedef ushort_t us8 __attribute__((ext_vector_type(8)));
typedef float f32x4 __attribute__((ext_vector_type(4)));

// ---------- helpers ----------
__device__ __forceinline__ ushort_t f2bf(float f) {
  union { float f; uint32_t u; } x; x.f = f;
  uint32_t r = (x.u + 0x7fffu + ((x.u >> 16) & 1u)) >> 16;
  return (ushort_t)r;
}
__device__ __forceinline__ float bf2f(ushort_t u) {
  union { uint32_t u; float f; } x; x.u = ((uint32_t)u) << 16;
  return x.f;
}
__device__ __forceinline__ float exp2_hw(float x) {
  float r;
  asm volatile("v_exp_f32 %0, %1\n\ts_nop 0" : "=v"(r) : "v"(x));
  return r;
}
__device__ __forceinline__ void gload_lds16(const void* g, void* l) {
  __builtin_amdgcn_global_load_lds(
      (const __attribute__((address_space(1))) void*)g,
      (__attribute__((address_space(3))) void*)l, 16, 0, 0);
}

// ---------- fp32 -> bf16 convert ----------
__global__ void f32_to_bf16_kn(const float* __restrict__ in,
                               ushort_t* __restrict__ out, int n) {
  int i = (blockIdx.x * blockDim.x + threadIdx.x) * 4;
  if (i >= n) return;
  float4 v = *(const float4*)(in + i);
  ushort4 o;
  o.x = f2bf(v.x); o.y = f2bf(v.y); o.z = f2bf(v.z); o.w = f2bf(v.w);
  *(ushort4*)(out + i) = o;
}

// ---------- fused 4-weight convert ----------
__global__ void wconvert_kn(const float* __restrict__ Wq, const float* __restrict__ Wk,
                            const float* __restrict__ Wv, const float* __restrict__ Wo,
                            ushort_t* __restrict__ out) {
  int i = (blockIdx.x * blockDim.x + threadIdx.x) * 4;
  const float* src;
  int off;
  if (i < 4194304)      { src = Wq; off = i; }
  else if (i < 5242880) { src = Wk; off = i - 4194304; }
  else if (i < 6291456) { src = Wv; off = i - 5242880; }
  else                  { src = Wo; off = i - 6291456; }
  float4 v = *(const float4*)(src + off);
  ushort4 o;
  o.x = f2bf(v.x); o.y = f2bf(v.y); o.z = f2bf(v.z); o.w = f2bf(v.w);
  *(ushort4*)(out + i) = o;
}

// ---------- 256x256 deep-pipelined BT GEMM (m201-style) ----------
// C[m][n] = sum_k A[m][k]*B[n][k].  BK=64, 8 waves (2Mx4N), per-wave 128x64.
// LDS: dbuf x (A 256x64 + B 256x64) bf16 = 128 KiB.
// Swizzle: LDS slot c within a 128B row holds global k-slot c^(row&7)
//   (linear gload_lds dest + inverse-swizzled global src + swizzled ds_read).
// Pipeline: stage(t+1); vmcnt(8) [tile t landed, t+1 in flight]; s_barrier;
//   compute(t); s_barrier.  Raw barriers — no vmcnt(0) drain in the loop.
// OUT_MODE 1: fp32 row-major [M][N].  OUT_MODE 2: fused QKV scatter.
template <int OUT_MODE>
__global__ __launch_bounds__(512, 2) void gemm256(
    const ushort_t* __restrict__ A, const ushort_t* __restrict__ Bw,
    void* __restrict__ Cout, void* __restrict__ Cout2, int M, int N, int K) {
  __shared__ __align__(16) ushort_t lds[2][2][256 * 64];
  const int tid = threadIdx.x;
  const int lane = tid & 63;
  const int l15 = lane & 15, lq = lane >> 4;
  const int wid = tid >> 6;
  const int wr = wid >> 2, wc = wid & 3;
  const int m0 = blockIdx.x * 256, n0 = blockIdx.y * 256;

  // staging: per tile A = 4 chunks + B = 4 chunks; chunk = 8KB = 64 rows x 128B
  // thread covers LDS (row = tid>>3, slot = tid&7); global src slot = c^(row&7)
  const int sslot = (tid & 7) ^ ((tid >> 3) & 7);
  const int ldsWaveByte = wid * 1024;
  const size_t aRowBase = (size_t)(m0 + (tid >> 3)) * K + sslot * 8;
  const size_t bRowBase = (size_t)(n0 + (tid >> 3)) * K + sslot * 8;

  f32x4 acc[8][4] = {};
  const int nkt = K >> 6;

  // compute-side swizzled read offsets
  const int s7 = l15 & 7;
  const int aRow0 = (wr * 128 + l15) * 128;
  const int bRow0 = (wc * 64 + l15) * 128;
  const int oslot = (lq ^ s7) << 4;   // k2=0 slot byte; k2=1: ^64

#define STAGE256(t, buf)                                                      \
  {                                                                           \
    const int kOff_ = (t) * 64;                                               \
    _Pragma("unroll") for (int c = 0; c < 4; ++c)                             \
        gload_lds16(A + aRowBase + (size_t)c * 64 * K + kOff_,                \
                    (char*)&lds[buf][0][0] + c * 8192 + ldsWaveByte);         \
    _Pragma("unroll") for (int c = 0; c < 4; ++c)                             \
        gload_lds16(Bw + bRowBase + (size_t)c * 64 * K + kOff_,               \
                    (char*)&lds[buf][1][0] + c * 8192 + ldsWaveByte);         \
  }

  STAGE256(0, 0);
  for (int t = 0; t < nkt; ++t) {
    const int tn = (t + 1 < nkt) ? t + 1 : t;   // clamped prefetch (dest never read)
    STAGE256(tn, (t + 1) & 1);
    asm volatile("s_waitcnt vmcnt(8)" ::: "memory");
    __builtin_amdgcn_s_barrier();
    __builtin_amdgcn_sched_barrier(0);
    const ushort_t* As = &lds[t & 1][0][0];
    const ushort_t* Bs = &lds[t & 1][1][0];
#pragma unroll
    for (int k2 = 0; k2 < 2; ++k2) {
      bf16x8 af[8], bfv[4];
      const int ob = oslot ^ (k2 << 6);
#pragma unroll
      for (int m = 0; m < 8; ++m)
        af[m] = *(const bf16x8*)((const char*)As + (aRow0 + m * 2048 + ob));
#pragma unroll
      for (int n = 0; n < 4; ++n)
        bfv[n] = *(const bf16x8*)((const char*)Bs + (bRow0 + n * 2048 + ob));
      __builtin_amdgcn_s_setprio(1);
#pragma unroll
      for (int m = 0; m < 8; ++m)
#pragma unroll
        for (int n = 0; n < 4; ++n)
          acc[m][n] = __builtin_amdgcn_mfma_f32_16x16x32_bf16(af[m], bfv[n],
                                                              acc[m][n], 0, 0, 0);
      __builtin_amdgcn_s_setprio(0);
    }
    __builtin_amdgcn_sched_barrier(0);
    __builtin_amdgcn_s_barrier();
  }
#undef STAGE256

  if (OUT_MODE == 1) {
    float* C = (float*)Cout;
#pragma unroll
    for (int m = 0; m < 8; ++m) {
      int row = m0 + wr * 128 + m * 16 + lq * 4;
#pragma unroll
      for (int n = 0; n < 4; ++n) {
        int col = n0 + wc * 64 + n * 16 + l15;
#pragma unroll
        for (int r = 0; r < 4; ++r)
          C[(size_t)(row + r) * N + col] = acc[m][n][r];
      }
    }
  } else {
    ushort_t* qr = (ushort_t*)Cout;
    ushort_t* kvr = (ushort_t*)Cout2;
#pragma unroll
    for (int m = 0; m < 8; ++m) {
      int row = m0 + wr * 128 + m * 16 + lq * 4;
#pragma unroll
      for (int n = 0; n < 4; ++n) {
        int col = n0 + wc * 64 + n * 16 + l15;
#pragma unroll
        for (int r = 0; r < 4; ++r) {
          int rr = row + r;
          int b = rr >> 11, s = rr & 2047;
          if (col < 2048) {
            int h = col >> 6, d = col & 63;
            qr[((size_t)(b * 32 + h) * 2048 + s) * 64 + d] = f2bf(acc[m][n][r]);
          } else {
            int n2 = col - 2048;
            int head = n2 >> 6, d = n2 & 63;
            kvr[((size_t)(b * 16 + head) * 2048 + s) * 64 + d] = f2bf(acc[m][n][r]);
          }
        }
      }
    }
  }
}

// ---------- in-place RoPE ----------
__global__ void rope_kn(ushort_t* __restrict__ X, int nh, int batch_stride,
                        float scale, int total) {
  int idx = blockIdx.x * blockDim.x + threadIdx.x;
  if (idx >= total) return;
  int p = idx & 31;
  int t = idx >> 5;
  int s = t & 2047;
  int bh = t >> 11;
  int h = bh % nh, b = bh / nh;
  ushort_t* row = X + (size_t)b * batch_stride + ((size_t)h * 2048 + s) * 64;
  float a = (float)s * __builtin_exp2f((float)p * -0.4152410118609203f);
  float sn, c;
  __sincosf(a, &sn, &c);
  float x0 = bf2f(row[p]), x1 = bf2f(row[p + 32]);
  row[p]      = f2bf((x0 * c - x1 * sn) * scale);
  row[p + 32] = f2bf((x1 * c + x0 * sn) * scale);
}

// ---------- causal GQA flash attention (fixed-max softmax) ----------
#define PAD_K 72
#define PAD_P 76
__global__ __launch_bounds__(256, 4) void attn_kn(
    const ushort_t* __restrict__ Q, const ushort_t* __restrict__ KV,
    ushort_t* __restrict__ ctx) {
  __shared__ __align__(16) ushort_t Ks[64 * PAD_K];
  __shared__ __align__(16) ushort_t Vs[80 * PAD_K];
  __shared__ __align__(16) ushort_t Ps[4][16 * PAD_P];
  const int tid = threadIdx.x, wid = tid >> 6, lane = tid & 63;
  const int l15 = lane & 15, lq = lane >> 4;
  const int g = blockIdx.x;
  const int bh = g & 63;
  const int qidx = g >> 6;
  const int jq = qidx >> 2, sl = qidx & 3;
  const int qb = (jq & 1) ? (12 - 4 * jq + sl) : (15 - 4 * jq - sl);
  const int b = bh >> 5, h = bh & 31, hk = h >> 2;
  const int q0 = qb * 128;
  const int wq0 = q0 + wid * 32;

  for (int i = tid; i < 16 * PAD_K; i += 256)
    Vs[64 * PAD_K + i] = (i < PAD_K) ? (ushort_t)0x3F80 : (ushort_t)0;

  const ushort_t* Qb = Q + ((size_t)(b * 32 + h) * 2048) * 64;
  const ushort_t* Kb = KV + ((size_t)(b * 16 + hk) * 2048) * 64;
  const ushort_t* Vb = KV + ((size_t)(b * 16 + 8 + hk) * 2048) * 64;

  bf16x8 qf[2][2];
#pragma unroll
  for (int qg = 0; qg < 2; ++qg)
#pragma unroll
    for (int ks = 0; ks < 2; ++ks)
      qf[qg][ks] = *(const bf16x8*)(Qb + (size_t)(wq0 + qg * 16 + l15) * 64 +
                                    ks * 32 + lq * 8);

  f32x4 acc[2][5] = {};

  const int srow = tid >> 3, sseg = tid & 7;
  const int vd = tid & 63, vkg = tid >> 6;

  const int nkt = 2 * qb + 2;
  us8 kr0, kr1, vr0, vr1;
  {
    kr0 = *(const us8*)(Kb + (size_t)srow * 64 + sseg * 8);
    kr1 = *(const us8*)(Kb + (size_t)(32 + srow) * 64 + sseg * 8);
#pragma unroll
    for (int i = 0; i < 8; ++i) vr0[i] = Vb[(size_t)(vkg * 16 + i) * 64 + vd];
#pragma unroll
    for (int i = 0; i < 8; ++i) vr1[i] = Vb[(size_t)(vkg * 16 + 8 + i) * 64 + vd];
  }

  for (int kt = 0; kt < nkt; ++kt) {
    const int k0 = kt * 64;
    __syncthreads();
    *(us8*)(Ks + srow * PAD_K + sseg * 8) = kr0;
    *(us8*)(Ks + (32 + srow) * PAD_K + sseg * 8) = kr1;
    *(us8*)(Vs + vd * PAD_K + vkg * 16) = vr0;
    *(us8*)(Vs + vd * PAD_K + vkg * 16 + 8) = vr1;
    if (kt + 1 < nkt) {
      const int k1 = k0 + 64;
      kr0 = *(const us8*)(Kb + (size_t)(k1 + srow) * 64 + sseg * 8);
      kr1 = *(const us8*)(Kb + (size_t)(k1 + 32 + srow) * 64 + sseg * 8);
#pragma unroll
      for (int i = 0; i < 8; ++i)
        vr0[i] = Vb[(size_t)(k1 + vkg * 16 + i) * 64 + vd];
#pragma unroll
      for (int i = 0; i < 8; ++i)
        vr1[i] = Vb[(size_t)(k1 + vkg * 16 + 8 + i) * 64 + vd];
    }
    __syncthreads();

    if (k0 > wq0 + 31) continue;

#pragma unroll
    for (int qg = 0; qg < 2; ++qg) {
      const int rq0 = wq0 + qg * 16;
      f32x4 sf[4] = {};
      __builtin_amdgcn_s_setprio(1);
#pragma unroll
      for (int j = 0; j < 4; ++j)
#pragma unroll
        for (int ks = 0; ks < 2; ++ks)
          sf[j] = __builtin_amdgcn_mfma_f32_16x16x32_bf16(
              qf[qg][ks],
              *(const bf16x8*)(Ks + (j * 16 + l15) * PAD_K + ks * 32 + lq * 8),
              sf[j], 0, 0, 0);
      __builtin_amdgcn_s_setprio(0);

      if (k0 + 63 > rq0) {
#pragma unroll
        for (int j = 0; j < 4; ++j) {
          int kg = k0 + j * 16 + l15;
#pragma unroll
          for (int r = 0; r < 4; ++r) {
            int qrow = rq0 + lq * 4 + r;
            float p = (kg > qrow) ? 0.0f : exp2_hw(sf[j][r]);
            Ps[wid][(lq * 4 + r) * PAD_P + j * 16 + l15] = f2bf(p);
          }
        }
      } else {
#pragma unroll
        for (int j = 0; j < 4; ++j)
#pragma unroll
          for (int r = 0; r < 4; ++r)
            Ps[wid][(lq * 4 + r) * PAD_P + j * 16 + l15] = f2bf(exp2_hw(sf[j][r]));
      }

      bf16x8 pa[2];
#pragma unroll
      for (int ks = 0; ks < 2; ++ks)
        pa[ks] = *(const bf16x8*)(Ps[wid] + l15 * PAD_P + ks * 32 + lq * 8);

      __builtin_amdgcn_s_setprio(1);
#pragma unroll
      for (int dj = 0; dj < 5; ++dj) {
#pragma unroll
        for (int ks = 0; ks < 2; ++ks)
          acc[qg][dj] = __builtin_amdgcn_mfma_f32_16x16x32_bf16(
              pa[ks],
              *(const bf16x8*)(Vs + (dj * 16 + l15) * PAD_K + ks * 32 + lq * 8),
              acc[qg][dj], 0, 0, 0);
      }
      __builtin_amdgcn_s_setprio(0);
    }
  }

#pragma unroll
  for (int qg = 0; qg < 2; ++qg) {
    float linv[4];
#pragma unroll
    for (int r = 0; r < 4; ++r)
      linv[r] = 1.0f / __shfl(acc[qg][4][r], lane & 48);
#pragma unroll
    for (int dj = 0; dj < 4; ++dj)
#pragma unroll
      for (int r = 0; r < 4; ++r) {
        int qrow = wq0 + qg * 16 + lq * 4 + r;
        ctx[((size_t)(b * 2048 + qrow)) * 2048 + h * 64 + dj * 16 + l15] =
            f2bf(acc[qg][dj][r] * linv[r]);
      }
  }
}

// ---------- launch ----------
extern "C" void kernel_launch(void* const* d_in, const int* in_sizes, int n_in,
                              void* d_out, int out_size, void* d_ws, size_t ws_size,
                              hipStream_t stream) {
  const float* hs = (const float*)d_in[0];
  const float* Wq = (const float*)d_in[1];
  const float* Wk = (const float*)d_in[2];
  const float* Wv = (const float*)d_in[3];
  const float* Wo = (const float*)d_in[4];

  char* ws = (char*)d_ws;
  ushort_t* hb   = (ushort_t*)(ws);                        // 4096x2048 bf16
  ushort_t* wqb  = (ushort_t*)(ws + 16777216);             // [Wq;Wk;Wv;Wo] contiguous
  ushort_t* wob  = (ushort_t*)(ws + 29360128);             // Wo part
  ushort_t* qr   = (ushort_t*)(ws + 37748736);             // [2][32][2048][64]
  ushort_t* kvr  = (ushort_t*)(ws + 54525952);             // [2][16][2048][64]
  ushort_t* ctx  = hb;   // hb dead after projections

  f32_to_bf16_kn<<<8192, 256, 0, stream>>>(hs, hb, 8388608);
  wconvert_kn<<<10240, 256, 0, stream>>>(Wq, Wk, Wv, Wo, wqb);

  // fused QKV projection: N = 3072; 256^2 tiles -> grid (16,12)
  gemm256<2><<<dim3(16, 12), 512, 0, stream>>>(hb, wqb, qr, kvr, 4096, 3072, 2048);

  rope_kn<<<16384, 256, 0, stream>>>(qr, 32, 32 * 2048 * 64, 0.18033688f, 4194304);
  rope_kn<<<4096,  256, 0, stream>>>(kvr, 8, 16 * 2048 * 64, 1.0f, 1048576);

  attn_kn<<<dim3(1024), 256, 0, stream>>>(qr, kvr, ctx);

  // out projection: 256^2 tiles -> grid (16,8)
  gemm256<1><<<dim3(16, 8), 512, 0, stream>>>(ctx, wob, d_out, nullptr, 4096, 2048, 2048);
}

// Round 8
// 297.376 us; speedup vs baseline: 1.1115x; 1.1115x over previous
//
#include <hip/hip_runtime.h>
#include <cstdint>
#include <cstddef>

typedef unsigned short ushort_t;
typedef __bf16 bf16x8 __attribute__((ext_vector_type(8)));
typedef ushort_t us8 __attribute__((ext_vector_type(8)));
typedef float f32x4 __attribute__((ext_vector_type(4)));

// ---------- helpers ----------
__device__ __forceinline__ ushort_t f2bf(float f) {
  union { float f; uint32_t u; } x; x.f = f;
  uint32_t r = (x.u + 0x7fffu + ((x.u >> 16) & 1u)) >> 16;
  return (ushort_t)r;
}
__device__ __forceinline__ float bf2f(ushort_t u) {
  union { uint32_t u; float f; } x; x.u = ((uint32_t)u) << 16;
  return x.f;
}
__device__ __forceinline__ float exp2_hw(float x) {
  float r;
  asm volatile("v_exp_f32 %0, %1\n\ts_nop 0" : "=v"(r) : "v"(x));
  return r;
}
__device__ __forceinline__ void gload_lds16(const void* g, void* l) {
  __builtin_amdgcn_global_load_lds(
      (const __attribute__((address_space(1))) void*)g,
      (__attribute__((address_space(3))) void*)l, 16, 0, 0);
}

// ---------- fp32 -> bf16 convert ----------
__global__ void f32_to_bf16_kn(const float* __restrict__ in,
                               ushort_t* __restrict__ out, int n) {
  int i = (blockIdx.x * blockDim.x + threadIdx.x) * 4;
  if (i >= n) return;
  float4 v = *(const float4*)(in + i);
  ushort4 o;
  o.x = f2bf(v.x); o.y = f2bf(v.y); o.z = f2bf(v.z); o.w = f2bf(v.w);
  *(ushort4*)(out + i) = o;
}

// ---------- fused 4-weight convert ----------
__global__ void wconvert_kn(const float* __restrict__ Wq, const float* __restrict__ Wk,
                            const float* __restrict__ Wv, const float* __restrict__ Wo,
                            ushort_t* __restrict__ out) {
  int i = (blockIdx.x * blockDim.x + threadIdx.x) * 4;
  const float* src;
  int off;
  if (i < 4194304)      { src = Wq; off = i; }
  else if (i < 5242880) { src = Wk; off = i - 4194304; }
  else if (i < 6291456) { src = Wv; off = i - 5242880; }
  else                  { src = Wo; off = i - 6291456; }
  float4 v = *(const float4*)(src + off);
  ushort4 o;
  o.x = f2bf(v.x); o.y = f2bf(v.y); o.z = f2bf(v.z); o.w = f2bf(v.w);
  *(ushort4*)(out + i) = o;
}

// ---------- 128x128 counted-vmcnt pipelined BT GEMM ----------
// C[m][n] = sum_k A[m][k]*B[n][k].  BK=64, 4 waves (2Mx2N), per-wave 64x64.
// LDS: dbuf x (A 128x64 + B 128x64) bf16 = 64 KiB -> 2 blocks/CU.
// Swizzle: LDS 16B-slot c within a 128B row holds global k-slot c^(row&7)
//   (linear gload_lds dest + inverse-swizzled global src + swizzled ds_read).
// Pipeline: stage(t+1) [8 loads]; s_waitcnt vmcnt(8); s_barrier; compute(t);
//   s_barrier.  No vmcnt(0) drain in the loop.
// OUT_MODE 1: fp32 row-major [M][N].  OUT_MODE 2: fused QKV scatter.
template <int OUT_MODE>
__global__ __launch_bounds__(256, 2) void gemm128(
    const ushort_t* __restrict__ A, const ushort_t* __restrict__ Bw,
    void* __restrict__ Cout, void* __restrict__ Cout2, int M, int N, int K) {
  __shared__ __align__(16) ushort_t lds[2][2][128 * 64];
  const int tid = threadIdx.x;
  const int lane = tid & 63;
  const int l15 = lane & 15, lq = lane >> 4;
  const int wid = tid >> 6;
  const int wr = wid >> 1, wc = wid & 1;
  const int m0 = blockIdx.x * 128, n0 = blockIdx.y * 128;

  // staging: tile = 128 rows x 128B; 4 chunks of 32 rows; thread: row=tid>>3, slot=tid&7
  const int sslot = (tid & 7) ^ ((tid >> 3) & 7);
  const int ldsWaveByte = wid * 1024;
  const size_t aRowBase = (size_t)(m0 + (tid >> 3)) * K + sslot * 8;
  const size_t bRowBase = (size_t)(n0 + (tid >> 3)) * K + sslot * 8;

  f32x4 acc[4][4] = {};
  const int nkt = K >> 6;

  // compute-side swizzled read offsets (bytes)
  const int aRow0 = (wr * 64 + l15) * 128;
  const int bRow0 = (wc * 64 + l15) * 128;
  const int oslot = (lq ^ (l15 & 7)) << 4;   // k2=0; k2=1: ^64

#define STAGE128(t, buf)                                                      \
  {                                                                           \
    const int kOff_ = (t) * 64;                                               \
    _Pragma("unroll") for (int c = 0; c < 4; ++c)                             \
        gload_lds16(A + aRowBase + (size_t)c * 32 * K + kOff_,                \
                    (char*)&lds[buf][0][0] + c * 4096 + ldsWaveByte);         \
    _Pragma("unroll") for (int c = 0; c < 4; ++c)                             \
        gload_lds16(Bw + bRowBase + (size_t)c * 32 * K + kOff_,               \
                    (char*)&lds[buf][1][0] + c * 4096 + ldsWaveByte);         \
  }

  STAGE128(0, 0);
  for (int t = 0; t < nkt; ++t) {
    const int tn = (t + 1 < nkt) ? t + 1 : t;   // clamped prefetch (dest never read)
    STAGE128(tn, (t + 1) & 1);
    asm volatile("s_waitcnt vmcnt(8)" ::: "memory");
    __builtin_amdgcn_s_barrier();
    __builtin_amdgcn_sched_barrier(0);
    const ushort_t* As = &lds[t & 1][0][0];
    const ushort_t* Bs = &lds[t & 1][1][0];
#pragma unroll
    for (int k2 = 0; k2 < 2; ++k2) {
      bf16x8 af[4], bfv[4];
      const int ob = oslot ^ (k2 << 6);
#pragma unroll
      for (int m = 0; m < 4; ++m)
        af[m] = *(const bf16x8*)((const char*)As + (aRow0 + m * 2048 + ob));
#pragma unroll
      for (int n = 0; n < 4; ++n)
        bfv[n] = *(const bf16x8*)((const char*)Bs + (bRow0 + n * 2048 + ob));
      __builtin_amdgcn_s_setprio(1);
#pragma unroll
      for (int m = 0; m < 4; ++m)
#pragma unroll
        for (int n = 0; n < 4; ++n)
          acc[m][n] = __builtin_amdgcn_mfma_f32_16x16x32_bf16(af[m], bfv[n],
                                                              acc[m][n], 0, 0, 0);
      __builtin_amdgcn_s_setprio(0);
    }
    __builtin_amdgcn_sched_barrier(0);
    __builtin_amdgcn_s_barrier();
  }
#undef STAGE128

  if (OUT_MODE == 1) {
    float* C = (float*)Cout;
#pragma unroll
    for (int m = 0; m < 4; ++m) {
      int row = m0 + wr * 64 + m * 16 + lq * 4;
#pragma unroll
      for (int n = 0; n < 4; ++n) {
        int col = n0 + wc * 64 + n * 16 + l15;
#pragma unroll
        for (int r = 0; r < 4; ++r)
          C[(size_t)(row + r) * N + col] = acc[m][n][r];
      }
    }
  } else {
    ushort_t* qr = (ushort_t*)Cout;
    ushort_t* kvr = (ushort_t*)Cout2;
#pragma unroll
    for (int m = 0; m < 4; ++m) {
      int row = m0 + wr * 64 + m * 16 + lq * 4;
#pragma unroll
      for (int n = 0; n < 4; ++n) {
        int col = n0 + wc * 64 + n * 16 + l15;
#pragma unroll
        for (int r = 0; r < 4; ++r) {
          int rr = row + r;
          int b = rr >> 11, s = rr & 2047;
          if (col < 2048) {
            int h = col >> 6, d = col & 63;
            qr[((size_t)(b * 32 + h) * 2048 + s) * 64 + d] = f2bf(acc[m][n][r]);
          } else {
            int n2 = col - 2048;
            int head = n2 >> 6, d = n2 & 63;
            kvr[((size_t)(b * 16 + head) * 2048 + s) * 64 + d] = f2bf(acc[m][n][r]);
          }
        }
      }
    }
  }
}

// ---------- in-place RoPE ----------
__global__ void rope_kn(ushort_t* __restrict__ X, int nh, int batch_stride,
                        float scale, int total) {
  int idx = blockIdx.x * blockDim.x + threadIdx.x;
  if (idx >= total) return;
  int p = idx & 31;
  int t = idx >> 5;
  int s = t & 2047;
  int bh = t >> 11;
  int h = bh % nh, b = bh / nh;
  ushort_t* row = X + (size_t)b * batch_stride + ((size_t)h * 2048 + s) * 64;
  float a = (float)s * __builtin_exp2f((float)p * -0.4152410118609203f);
  float sn, c;
  __sincosf(a, &sn, &c);
  float x0 = bf2f(row[p]), x1 = bf2f(row[p + 32]);
  row[p]      = f2bf((x0 * c - x1 * sn) * scale);
  row[p + 32] = f2bf((x1 * c + x0 * sn) * scale);
}

// ---------- causal GQA flash attention (fixed-max softmax) ----------
#define PAD_K 72
#define PAD_P 76
__global__ __launch_bounds__(256, 4) void attn_kn(
    const ushort_t* __restrict__ Q, const ushort_t* __restrict__ KV,
    ushort_t* __restrict__ ctx) {
  __shared__ __align__(16) ushort_t Ks[64 * PAD_K];
  __shared__ __align__(16) ushort_t Vs[80 * PAD_K];
  __shared__ __align__(16) ushort_t Ps[4][16 * PAD_P];
  const int tid = threadIdx.x, wid = tid >> 6, lane = tid & 63;
  const int l15 = lane & 15, lq = lane >> 4;
  const int g = blockIdx.x;
  const int bh = g & 63;
  const int qidx = g >> 6;
  const int jq = qidx >> 2, sl = qidx & 3;
  const int qb = (jq & 1) ? (12 - 4 * jq + sl) : (15 - 4 * jq - sl);
  const int b = bh >> 5, h = bh & 31, hk = h >> 2;
  const int q0 = qb * 128;
  const int wq0 = q0 + wid * 32;

  for (int i = tid; i < 16 * PAD_K; i += 256)
    Vs[64 * PAD_K + i] = (i < PAD_K) ? (ushort_t)0x3F80 : (ushort_t)0;

  const ushort_t* Qb = Q + ((size_t)(b * 32 + h) * 2048) * 64;
  const ushort_t* Kb = KV + ((size_t)(b * 16 + hk) * 2048) * 64;
  const ushort_t* Vb = KV + ((size_t)(b * 16 + 8 + hk) * 2048) * 64;

  bf16x8 qf[2][2];
#pragma unroll
  for (int qg = 0; qg < 2; ++qg)
#pragma unroll
    for (int ks = 0; ks < 2; ++ks)
      qf[qg][ks] = *(const bf16x8*)(Qb + (size_t)(wq0 + qg * 16 + l15) * 64 +
                                    ks * 32 + lq * 8);

  f32x4 acc[2][5] = {};

  const int srow = tid >> 3, sseg = tid & 7;
  const int vd = tid & 63, vkg = tid >> 6;

  const int nkt = 2 * qb + 2;
  us8 kr0, kr1, vr0, vr1;
  {
    kr0 = *(const us8*)(Kb + (size_t)srow * 64 + sseg * 8);
    kr1 = *(const us8*)(Kb + (size_t)(32 + srow) * 64 + sseg * 8);
#pragma unroll
    for (int i = 0; i < 8; ++i) vr0[i] = Vb[(size_t)(vkg * 16 + i) * 64 + vd];
#pragma unroll
    for (int i = 0; i < 8; ++i) vr1[i] = Vb[(size_t)(vkg * 16 + 8 + i) * 64 + vd];
  }

  for (int kt = 0; kt < nkt; ++kt) {
    const int k0 = kt * 64;
    __syncthreads();
    *(us8*)(Ks + srow * PAD_K + sseg * 8) = kr0;
    *(us8*)(Ks + (32 + srow) * PAD_K + sseg * 8) = kr1;
    *(us8*)(Vs + vd * PAD_K + vkg * 16) = vr0;
    *(us8*)(Vs + vd * PAD_K + vkg * 16 + 8) = vr1;
    if (kt + 1 < nkt) {
      const int k1 = k0 + 64;
      kr0 = *(const us8*)(Kb + (size_t)(k1 + srow) * 64 + sseg * 8);
      kr1 = *(const us8*)(Kb + (size_t)(k1 + 32 + srow) * 64 + sseg * 8);
#pragma unroll
      for (int i = 0; i < 8; ++i)
        vr0[i] = Vb[(size_t)(k1 + vkg * 16 + i) * 64 + vd];
#pragma unroll
      for (int i = 0; i < 8; ++i)
        vr1[i] = Vb[(size_t)(k1 + vkg * 16 + 8 + i) * 64 + vd];
    }
    __syncthreads();

    if (k0 > wq0 + 31) continue;

#pragma unroll
    for (int qg = 0; qg < 2; ++qg) {
      const int rq0 = wq0 + qg * 16;
      f32x4 sf[4] = {};
      __builtin_amdgcn_s_setprio(1);
#pragma unroll
      for (int j = 0; j < 4; ++j)
#pragma unroll
        for (int ks = 0; ks < 2; ++ks)
          sf[j] = __builtin_amdgcn_mfma_f32_16x16x32_bf16(
              qf[qg][ks],
              *(const bf16x8*)(Ks + (j * 16 + l15) * PAD_K + ks * 32 + lq * 8),
              sf[j], 0, 0, 0);
      __builtin_amdgcn_s_setprio(0);

      if (k0 + 63 > rq0) {
#pragma unroll
        for (int j = 0; j < 4; ++j) {
          int kg = k0 + j * 16 + l15;
#pragma unroll
          for (int r = 0; r < 4; ++r) {
            int qrow = rq0 + lq * 4 + r;
            float p = (kg > qrow) ? 0.0f : exp2_hw(sf[j][r]);
            Ps[wid][(lq * 4 + r) * PAD_P + j * 16 + l15] = f2bf(p);
          }
        }
      } else {
#pragma unroll
        for (int j = 0; j < 4; ++j)
#pragma unroll
          for (int r = 0; r < 4; ++r)
            Ps[wid][(lq * 4 + r) * PAD_P + j * 16 + l15] = f2bf(exp2_hw(sf[j][r]));
      }

      bf16x8 pa[2];
#pragma unroll
      for (int ks = 0; ks < 2; ++ks)
        pa[ks] = *(const bf16x8*)(Ps[wid] + l15 * PAD_P + ks * 32 + lq * 8);

      __builtin_amdgcn_s_setprio(1);
#pragma unroll
      for (int dj = 0; dj < 5; ++dj) {
#pragma unroll
        for (int ks = 0; ks < 2; ++ks)
          acc[qg][dj] = __builtin_amdgcn_mfma_f32_16x16x32_bf16(
              pa[ks],
              *(const bf16x8*)(Vs + (dj * 16 + l15) * PAD_K + ks * 32 + lq * 8),
              acc[qg][dj], 0, 0, 0);
      }
      __builtin_amdgcn_s_setprio(0);
    }
  }

#pragma unroll
  for (int qg = 0; qg < 2; ++qg) {
    float linv[4];
#pragma unroll
    for (int r = 0; r < 4; ++r)
      linv[r] = 1.0f / __shfl(acc[qg][4][r], lane & 48);
#pragma unroll
    for (int dj = 0; dj < 4; ++dj)
#pragma unroll
      for (int r = 0; r < 4; ++r) {
        int qrow = wq0 + qg * 16 + lq * 4 + r;
        ctx[((size_t)(b * 2048 + qrow)) * 2048 + h * 64 + dj * 16 + l15] =
            f2bf(acc[qg][dj][r] * linv[r]);
      }
  }
}

// ---------- launch ----------
extern "C" void kernel_launch(void* const* d_in, const int* in_sizes, int n_in,
                              void* d_out, int out_size, void* d_ws, size_t ws_size,
                              hipStream_t stream) {
  const float* hs = (const float*)d_in[0];
  const float* Wq = (const float*)d_in[1];
  const float* Wk = (const float*)d_in[2];
  const float* Wv = (const float*)d_in[3];
  const float* Wo = (const float*)d_in[4];

  char* ws = (char*)d_ws;
  ushort_t* hb   = (ushort_t*)(ws);                        // 4096x2048 bf16
  ushort_t* wqb  = (ushort_t*)(ws + 16777216);             // [Wq;Wk;Wv;Wo] contiguous
  ushort_t* wob  = (ushort_t*)(ws + 29360128);             // Wo part
  ushort_t* qr   = (ushort_t*)(ws + 37748736);             // [2][32][2048][64]
  ushort_t* kvr  = (ushort_t*)(ws + 54525952);             // [2][16][2048][64]
  ushort_t* ctx  = hb;   // hb dead after projections

  f32_to_bf16_kn<<<8192, 256, 0, stream>>>(hs, hb, 8388608);
  wconvert_kn<<<10240, 256, 0, stream>>>(Wq, Wk, Wv, Wo, wqb);

  // fused QKV projection: N = 3072 -> grid (32,24) = 768 blocks
  gemm128<2><<<dim3(32, 24), 256, 0, stream>>>(hb, wqb, qr, kvr, 4096, 3072, 2048);

  rope_kn<<<16384, 256, 0, stream>>>(qr, 32, 32 * 2048 * 64, 0.18033688f, 4194304);
  rope_kn<<<4096,  256, 0, stream>>>(kvr, 8, 16 * 2048 * 64, 1.0f, 1048576);

  attn_kn<<<dim3(1024), 256, 0, stream>>>(qr, kvr, ctx);

  // out projection -> grid (32,16) = 512 blocks
  gemm128<1><<<dim3(32, 16), 256, 0, stream>>>(ctx, wob, d_out, nullptr, 4096, 2048, 2048);
}